// Round 7
// baseline (240.797 us; speedup 1.0000x reference)
//
#include <hip/hip_runtime.h>

// int8 quantized conv2d 3x3 s1 p1. B=32 Cin=128 H=W=56 Cout=256.
// Implicit GEMM. A(weights) via 3-deep LDS ring (24KB, gld_lds 2 chunks ahead),
// B(activations) direct global->reg 3-deep ring (2 chunks ahead, L2-resident).
// 256-thr blocks, 128co x 128px, 3 blocks/CU, counted vmcnt(6), 1 barrier/chunk.
// XCD-swizzled grid. B bytes identical to LDS path -> numerics exact.

#define B_    32
#define CIN   128
#define H_    56
#define W_    56
#define COUT  256
#define HP    58
#define WP    58
#define HWP   (H_*W_)        // 3136
#define NPIX  (B_*HWP)       // 100352
#define NCHUNK 18            // K=1152 / 64
#define WCHUNK 16384         // wq bytes per chunk = 256co * 64B

typedef int int4v __attribute__((ext_vector_type(4)));

__device__ __forceinline__ void gld_lds16(const void* g, void* l) {
    __builtin_amdgcn_global_load_lds(
        (const __attribute__((address_space(1))) unsigned int*)g,
        (__attribute__((address_space(3))) unsigned int*)l, 16, 0, 0);
}

// ---------------- fused amax over x and w ----------------
__global__ __launch_bounds__(256) void amax_kernel(const float4* __restrict__ x, long n4x,
                                                   const float4* __restrict__ wt, long n4w,
                                                   unsigned* __restrict__ scales) {
    const float4* p; long n4; unsigned* slot; long start, stride;
    if (blockIdx.x < 2048) {
        p = x; n4 = n4x; slot = scales;
        start = (long)blockIdx.x * 256 + threadIdx.x; stride = 2048L * 256;
    } else {
        p = wt; n4 = n4w; slot = scales + 1;
        start = (long)(blockIdx.x - 2048) * 256 + threadIdx.x; stride = 128L * 256;
    }
    float m = 0.f;
    for (long i = start; i < n4; i += stride) {
        float4 v = p[i];
        m = fmaxf(m, fmaxf(fmaxf(fabsf(v.x), fabsf(v.y)), fmaxf(fabsf(v.z), fabsf(v.w))));
    }
    __shared__ float red[256];
    red[threadIdx.x] = m; __syncthreads();
    for (int s = 128; s > 0; s >>= 1) {
        if (threadIdx.x < s) red[threadIdx.x] = fmaxf(red[threadIdx.x], red[threadIdx.x + s]);
        __syncthreads();
    }
    if (threadIdx.x == 0) atomicMax(slot, __float_as_uint(red[0]));  // all >=0
}

// ---------------- quantize x: NCHW f32 -> padded NHWC int8 (+ border zeroing) ----------------
__global__ __launch_bounds__(256) void quant_x_kernel(const float* __restrict__ x,
        const unsigned* __restrict__ scales, signed char* __restrict__ xq) {
    const int bh = blockIdx.x;
    const int b = bh / H_, h = bh % H_;
    const float sx = 127.0f / __uint_as_float(scales[0]);
    __shared__ int ldsq[W_ * 33];
    const int tid = threadIdx.x;

    // ---- border padding; disjoint rows per block ----
    int4 z; z.x = 0; z.y = 0; z.z = 0; z.w = 0;
    int4* prow = (int4*)(xq + ((long)b * HP + h + 1) * WP * CIN);
    if (tid < 8) prow[tid] = z;                       // col 0 of padded row h+1
    else if (tid < 16) prow[456 + tid - 8] = z;       // col 57 (57*8=456)
    if (h == 0) {
        int4* r0 = (int4*)(xq + (long)b * HP * WP * CIN);
        for (int i = tid; i < 464; i += 256) r0[i] = z;       // padded row 0
    } else if (h == H_ - 1) {
        int4* rt = (int4*)(xq + ((long)b * HP + 57) * WP * CIN);
        for (int i = tid; i < 464; i += 256) rt[i] = z;       // padded row 57
    }

    const int w = tid & 63;
    const int chi = tid >> 6;   // 0..3
    if (w < W_) {
        const float* xb = x + (long)b * CIN * HWP + h * W_ + w;
#pragma unroll
        for (int it = 0; it < 8; ++it) {
            const int c4 = it * 4 + chi;     // 0..31
            int pk = 0;
#pragma unroll
            for (int u = 0; u < 4; ++u) {
                float v = xb[(long)(c4 * 4 + u) * HWP];
                float q = fminf(127.f, fmaxf(-127.f, rintf(v * sx)));
                pk |= ((int)q & 0xff) << (u * 8);
            }
            ldsq[w * 33 + c4] = pk;
        }
    }
    __syncthreads();
    int4* dst = (int4*)(xq + (((long)b * HP + h + 1) * WP + 1) * CIN);
    for (int idx = tid; idx < W_ * 8; idx += 256) {
        const int ww = idx >> 3, c16 = idx & 7;
        int4 v;
        v.x = ldsq[ww * 33 + c16 * 4 + 0];
        v.y = ldsq[ww * 33 + c16 * 4 + 1];
        v.z = ldsq[ww * 33 + c16 * 4 + 2];
        v.w = ldsq[ww * 33 + c16 * 4 + 3];
        dst[ww * 8 + c16] = v;
    }
}

// ---------------- quantize w: OIHW f32 -> packed [chunk][cohalf][g][co128][16] int8 ----------------
__global__ __launch_bounds__(256) void quant_w_kernel(const float* __restrict__ wt,
        const unsigned* __restrict__ scales, signed char* __restrict__ wq) {
    const int id = blockIdx.x * 256 + threadIdx.x;   // 73728 total
    if (id >= COUT * 9 * 32) return;
    const float sw = 127.0f / __uint_as_float(scales[1]);
    const int co = id / 288;
    const int r  = id % 288;
    const int t  = r / 32;    // tap
    const int c4 = r % 32;    // ci/4
    int pk = 0;
#pragma unroll
    for (int u = 0; u < 4; ++u) {
        float v = wt[(co * CIN + c4 * 4 + u) * 9 + t];
        float q = fminf(127.f, fmaxf(-127.f, rintf(v * sw)));
        pk |= ((int)q & 0xff) << (u * 8);
    }
    const int k = t * CIN + c4 * 4;
    const int chunk = k >> 6;
    const int o = k & 63;
    *(int*)(wq + (long)chunk * WCHUNK + (co >> 7) * 8192 +
            (o >> 4) * 2048 + (co & 127) * 16 + (o & 15)) = pk;
}

// ---------------- conv: A-LDS ring + B-reg ring (both 2-deep), counted-vmcnt ----------------
// 256 thr = 4 waves; tile 128 co x 128 px; wave tile 64x64 (2x2 waves).
// LDS: A ring 3x8KB = 24KB -> 3 blocks/CU. B: 3x16 VGPR ring, loaded 2 chunks ahead.
// Body(c): {vmcnt(6); s_barrier} -> STAGE_A(c+2) [2 gld_lds] -> LOADB(c+2) [4 dwordx4]
//          -> ds_read 4 A-frags -> 16 MFMA (B from regs).
// FIFO: each body issues 6 VMEM ops; at TOP(c) bodies (c-2),(c-1) outstanding (12) ->
// vmcnt(6) retires A(c)+B(c), keeps body(c-1)'s 6 in flight. Tail TOP(17): vmcnt(0).
// Bodies contained between "memory"-clobber asm barriers -> no in-loop sched pins.
__global__ __launch_bounds__(256, 3) void conv_kernel(
        const signed char* __restrict__ xq, const signed char* __restrict__ wq,
        const float* __restrict__ bias, const unsigned* __restrict__ scales,
        float* __restrict__ out) {
    __shared__ signed char smem[24576];   // A ring; epilogue reuses as f32 scratch

    const int tid = threadIdx.x;
    const int lane = tid & 63;
    const int wv = tid >> 6;        // 0..3
    const int ln = lane & 15;
    const int g  = lane >> 4;

    const int wco2 = wv >> 1;       // co half within block-co-tile
    const int wpx2 = wv & 1;        // px half

    // XCD-aware swizzle: 1568 blocks = 8 XCDs * 196; wg pairs share px tile (B L2 reuse)
    const int bid = blockIdx.x;
    const int wg  = (bid & 7) * 196 + (bid >> 3);
    const int pxt = wg >> 1;
    const int cot = wg & 1;
    const int px_blk = pxt * 128;
    const int cotoff = cot * 8192;

    // A staging: wave stages 2x1KB contiguous (wq slice layout == A-LDS layout)
    const int aoff0 = wv * 1024 + lane * 16;
    const int aoff1 = aoff0 + 4096;

    // B per-lane voffsets: frag j, lane (ln,g) -> xq[px(j,ln), k = g*16 ...]
    int voff[4];
#pragma unroll
    for (int j = 0; j < 4; ++j) {
        const int pxs = px_blk + wpx2 * 64 + j * 16 + ln;
        const int bS = pxs / HWP, hwS = pxs % HWP;
        const int hS = hwS / W_, wS = hwS % W_;
        voff[j] = ((bS * HP + hS) * WP + wS) * CIN + g * 16;
    }
    const int voff0 = voff[0], voff1 = voff[1], voff2 = voff[2], voff3 = voff[3];

#define STAGE_A(c) { const int bf_ = (c) % 3; \
    gld_lds16(wq + (c) * WCHUNK + cotoff + aoff0, &smem[bf_ * 8192 + aoff0]); \
    gld_lds16(wq + (c) * WCHUNK + cotoff + aoff1, &smem[bf_ * 8192 + aoff1]); }

#define LOADB(c, P) { const int tap_ = (c) >> 1; \
    const signed char* p_ = xq + ((tap_ / 3) * WP + (tap_ % 3)) * CIN + ((c) & 1) * 64; \
    P##0 = *(const int4v*)(p_ + voff0); P##1 = *(const int4v*)(p_ + voff1); \
    P##2 = *(const int4v*)(p_ + voff2); P##3 = *(const int4v*)(p_ + voff3); }

#define LDA_(i) (*(const int4v*)&smem[buf * 8192 + g * 2048 + (wco2 * 64 + (i) * 16 + ln) * 16])
#define MM(i, j, A, Bv) acc[i][j] = __builtin_amdgcn_mfma_i32_16x16x64_i8(A, Bv, acc[i][j], 0, 0, 0)

#define CHUNK(c, VM, U, L) { \
    const int buf = (c) % 3; \
    asm volatile("s_waitcnt vmcnt(" #VM ")\n\ts_barrier" ::: "memory"); \
    if ((c) + 2 < NCHUNK) { STAGE_A((c) + 2); LOADB((c) + 2, L); } \
    int4v Af0 = LDA_(0), Af1 = LDA_(1), Af2 = LDA_(2), Af3 = LDA_(3); \
    __builtin_amdgcn_s_setprio(1); \
    MM(0, 0, Af0, U##0); MM(0, 1, Af0, U##1); MM(0, 2, Af0, U##2); MM(0, 3, Af0, U##3); \
    MM(1, 0, Af1, U##0); MM(1, 1, Af1, U##1); MM(1, 2, Af1, U##2); MM(1, 3, Af1, U##3); \
    MM(2, 0, Af2, U##0); MM(2, 1, Af2, U##1); MM(2, 2, Af2, U##2); MM(2, 3, Af2, U##3); \
    MM(3, 0, Af3, U##0); MM(3, 1, Af3, U##1); MM(3, 2, Af3, U##2); MM(3, 3, Af3, U##3); \
    __builtin_amdgcn_s_setprio(0); }

    int4v acc[4][4] = {};
    int4v P00, P01, P02, P03, P10, P11, P12, P13, P20, P21, P22, P23;
    // Prologue, issue-order pinned for FIFO counting: A(0) B(0) A(1) B(1)
    STAGE_A(0);
    __builtin_amdgcn_sched_barrier(0);
    LOADB(0, P0);
    __builtin_amdgcn_sched_barrier(0);
    STAGE_A(1);
    __builtin_amdgcn_sched_barrier(0);
    LOADB(1, P1);
    // body c: uses buf c%3, loads buf (c+2)%3
    CHUNK(0,  6, P0, P2) CHUNK(1,  6, P1, P0) CHUNK(2,  6, P2, P1)
    CHUNK(3,  6, P0, P2) CHUNK(4,  6, P1, P0) CHUNK(5,  6, P2, P1)
    CHUNK(6,  6, P0, P2) CHUNK(7,  6, P1, P0) CHUNK(8,  6, P2, P1)
    CHUNK(9,  6, P0, P2) CHUNK(10, 6, P1, P0) CHUNK(11, 6, P2, P1)
    CHUNK(12, 6, P0, P2) CHUNK(13, 6, P1, P0) CHUNK(14, 6, P2, P1)
    CHUNK(15, 6, P0, P2) CHUNK(16, 6, P1, P0) CHUNK(17, 0, P2, P0)
#undef CHUNK
#undef MM
#undef LDA_
#undef LOADB
#undef STAGE_A

    const float ax = __uint_as_float(scales[0]);
    const float aw = __uint_as_float(scales[1]);
    const float inv = 1.0f / ((127.0f / ax) * (127.0f / aw));

    // -------- epilogue: LDS transpose in 32-co rounds -> float4 stores --------
    // acc (i,j,r): co = cot*128 + wco2*64 + i*16 + g*4 + r; px = px_blk + wpx2*64 + j*16 + ln
    __syncthreads();
    float* ldsT = (float*)smem;            // [32 rows][stride 130 f32] = 16640 B

    const int c4 = tid & 31;               // float4 px column
    const int rsel = tid >> 5;             // 0..7
    const int px4 = px_blk + c4 * 4;
    const int bb = px4 / HWP, hw = px4 - bb * HWP;
    float* outb = out + ((long)bb * COUT + cot * 128) * HWP + hw;

#pragma unroll
    for (int rnd = 0; rnd < 4; ++rnd) {
        if (wco2 == (rnd >> 1)) {          // the 2 waves holding this 32-co band stage it
#pragma unroll
            for (int ii = 0; ii < 2; ++ii) {
                const int i = (rnd & 1) * 2 + ii;
#pragma unroll
                for (int r = 0; r < 4; ++r) {
                    const int cl = ii * 16 + g * 4 + r;   // 0..31
#pragma unroll
                    for (int j = 0; j < 4; ++j)
                        ldsT[cl * 130 + wpx2 * 64 + j * 16 + ln] = (float)acc[i][j][r] * inv;
                }
            }
        }
        __syncthreads();
#pragma unroll
        for (int rr = 0; rr < 4; ++rr) {
            const int row = rr * 8 + rsel;             // 0..31
            const int co = rnd * 32 + row;             // block-local co
            float4 v = *(float4*)&ldsT[row * 130 + c4 * 4];
            const float bsv = bias[cot * 128 + co];
            v.x += bsv; v.y += bsv; v.z += bsv; v.w += bsv;
            *(float4*)&outb[(long)co * HWP] = v;
        }
        if (rnd < 3) __syncthreads();
    }
}

extern "C" void kernel_launch(void* const* d_in, const int* in_sizes, int n_in,
                              void* d_out, int out_size, void* d_ws, size_t ws_size,
                              hipStream_t stream) {
    const float* x  = (const float*)d_in[0];
    const float* wt = (const float*)d_in[1];
    const float* bs = (const float*)d_in[2];
    float* out = (float*)d_out;

    unsigned* scales = (unsigned*)d_ws;                  // [0]=amax_x, [1]=amax_w (bits)
    const size_t XQ_OFF   = 256;
    const size_t XQ_BYTES = (size_t)B_ * HP * WP * CIN;  // 13,778,944
    signed char* xq = (signed char*)d_ws + XQ_OFF;
    signed char* wq = xq + XQ_BYTES;

    hipMemsetAsync(d_ws, 0, 8, stream);                  // zero the two amax slots

    const long n4x = (long)B_ * CIN * H_ * W_ / 4;
    const long n4w = (long)COUT * CIN * 9 / 4;
    amax_kernel<<<2176, 256, 0, stream>>>((const float4*)x, n4x, (const float4*)wt, n4w, scales);

    quant_x_kernel<<<B_ * H_, 256, 0, stream>>>(x, scales, xq);
    quant_w_kernel<<<(COUT * 9 * 32 + 255) / 256, 256, 0, stream>>>(wt, scales, wq);

    conv_kernel<<<2 * NPIX / 128, 256, 0, stream>>>(xq, wq, bs, scales, out);
}

// Round 8
// 221.495 us; speedup vs baseline: 1.0871x; 1.0871x over previous
//
#include <hip/hip_runtime.h>

// int8 quantized conv2d 3x3 s1 p1. B=32 Cin=128 H=W=56 Cout=256.
// Implicit GEMM with RAW INPUT WINDOW reuse: each block stages its 2-output-row
// input window (4 padded rows x 58 x 128 = 29696B) ONCE (coalesced, reg->LDS
// transposed [ci16][px58][16]); K-loop stages only A (3-deep LDS ring, gld_lds
// 2 ahead, vmcnt(2), 1 barrier/chunk). 256 thr, 128co x 112px, 3 blocks/CU.

#define B_    32
#define CIN   128
#define H_    56
#define W_    56
#define COUT  256
#define HP    58
#define WP    58
#define HWP   (H_*W_)        // 3136
#define NPIX  (B_*HWP)       // 100352
#define NCHUNK 18            // K=1152 / 64
#define WCHUNK 16384         // wq bytes per chunk = 256co * 64B
#define BWIN  24576          // LDS offset of B window
#define GSTR  3712           // B window stride per ci16 group = 232*16

typedef int int4v __attribute__((ext_vector_type(4)));

__device__ __forceinline__ void gld_lds16(const void* g, void* l) {
    __builtin_amdgcn_global_load_lds(
        (const __attribute__((address_space(1))) unsigned int*)g,
        (__attribute__((address_space(3))) unsigned int*)l, 16, 0, 0);
}

// ---------------- fused amax over x and w ----------------
__global__ __launch_bounds__(256) void amax_kernel(const float4* __restrict__ x, long n4x,
                                                   const float4* __restrict__ wt, long n4w,
                                                   unsigned* __restrict__ scales) {
    const float4* p; long n4; unsigned* slot; long start, stride;
    if (blockIdx.x < 2048) {
        p = x; n4 = n4x; slot = scales;
        start = (long)blockIdx.x * 256 + threadIdx.x; stride = 2048L * 256;
    } else {
        p = wt; n4 = n4w; slot = scales + 1;
        start = (long)(blockIdx.x - 2048) * 256 + threadIdx.x; stride = 128L * 256;
    }
    float m = 0.f;
    for (long i = start; i < n4; i += stride) {
        float4 v = p[i];
        m = fmaxf(m, fmaxf(fmaxf(fabsf(v.x), fabsf(v.y)), fmaxf(fabsf(v.z), fabsf(v.w))));
    }
    __shared__ float red[256];
    red[threadIdx.x] = m; __syncthreads();
    for (int s = 128; s > 0; s >>= 1) {
        if (threadIdx.x < s) red[threadIdx.x] = fmaxf(red[threadIdx.x], red[threadIdx.x + s]);
        __syncthreads();
    }
    if (threadIdx.x == 0) atomicMax(slot, __float_as_uint(red[0]));  // all >=0
}

// ---------------- quantize x: NCHW f32 -> padded NHWC int8 (+ border zeroing) ----------------
__global__ __launch_bounds__(256) void quant_x_kernel(const float* __restrict__ x,
        const unsigned* __restrict__ scales, signed char* __restrict__ xq) {
    const int bh = blockIdx.x;
    const int b = bh / H_, h = bh % H_;
    const float sx = 127.0f / __uint_as_float(scales[0]);
    __shared__ int ldsq[W_ * 33];
    const int tid = threadIdx.x;

    // ---- border padding; disjoint rows per block ----
    int4 z; z.x = 0; z.y = 0; z.z = 0; z.w = 0;
    int4* prow = (int4*)(xq + ((long)b * HP + h + 1) * WP * CIN);
    if (tid < 8) prow[tid] = z;                       // col 0 of padded row h+1
    else if (tid < 16) prow[456 + tid - 8] = z;       // col 57 (57*8=456)
    if (h == 0) {
        int4* r0 = (int4*)(xq + (long)b * HP * WP * CIN);
        for (int i = tid; i < 464; i += 256) r0[i] = z;       // padded row 0
    } else if (h == H_ - 1) {
        int4* rt = (int4*)(xq + ((long)b * HP + 57) * WP * CIN);
        for (int i = tid; i < 464; i += 256) rt[i] = z;       // padded row 57
    }

    const int w = tid & 63;
    const int chi = tid >> 6;   // 0..3
    if (w < W_) {
        const float* xb = x + (long)b * CIN * HWP + h * W_ + w;
#pragma unroll
        for (int it = 0; it < 8; ++it) {
            const int c4 = it * 4 + chi;     // 0..31
            int pk = 0;
#pragma unroll
            for (int u = 0; u < 4; ++u) {
                float v = xb[(long)(c4 * 4 + u) * HWP];
                float q = fminf(127.f, fmaxf(-127.f, rintf(v * sx)));
                pk |= ((int)q & 0xff) << (u * 8);
            }
            ldsq[w * 33 + c4] = pk;
        }
    }
    __syncthreads();
    int4* dst = (int4*)(xq + (((long)b * HP + h + 1) * WP + 1) * CIN);
    for (int idx = tid; idx < W_ * 8; idx += 256) {
        const int ww = idx >> 3, c16 = idx & 7;
        int4 v;
        v.x = ldsq[ww * 33 + c16 * 4 + 0];
        v.y = ldsq[ww * 33 + c16 * 4 + 1];
        v.z = ldsq[ww * 33 + c16 * 4 + 2];
        v.w = ldsq[ww * 33 + c16 * 4 + 3];
        dst[ww * 8 + c16] = v;
    }
}

// ---------------- quantize w: OIHW f32 -> packed [chunk][cohalf][g][co128][16] int8 ----------------
__global__ __launch_bounds__(256) void quant_w_kernel(const float* __restrict__ wt,
        const unsigned* __restrict__ scales, signed char* __restrict__ wq) {
    const int id = blockIdx.x * 256 + threadIdx.x;   // 73728 total
    if (id >= COUT * 9 * 32) return;
    const float sw = 127.0f / __uint_as_float(scales[1]);
    const int co = id / 288;
    const int r  = id % 288;
    const int t  = r / 32;    // tap
    const int c4 = r % 32;    // ci/4
    int pk = 0;
#pragma unroll
    for (int u = 0; u < 4; ++u) {
        float v = wt[(co * CIN + c4 * 4 + u) * 9 + t];
        float q = fminf(127.f, fmaxf(-127.f, rintf(v * sw)));
        pk |= ((int)q & 0xff) << (u * 8);
    }
    const int k = t * CIN + c4 * 4;
    const int chunk = k >> 6;
    const int o = k & 63;
    *(int*)(wq + (long)chunk * WCHUNK + (co >> 7) * 8192 +
            (o >> 4) * 2048 + (co & 127) * 16 + (o & 15)) = pk;
}

// ---------------- conv: raw-window B + A-LDS ring, counted-vmcnt MFMA implicit GEMM ----------------
// 256 thr = 4 waves; tile 128 co x 112 px (2 output rows); wave = 32 co x 112 px.
// LDS: A ring 3x8KB @ [0,24576); B window 29696B @ [24576,54272) as [ci16 g][px58][16].
// Prologue: B window coalesced global->reg->LDS (transposed), then A(0),A(1) gld_lds.
// Per chunk: {vmcnt(2); s_barrier} -> STAGE_A(c+2) -> ds_read 2A + 7B frags -> 14 MFMA.
// B frag (j, lane ln,g, chunk c): window pixel (ph+th)*58 + pw+tw, ci = (c&1)*64+g*16.
__global__ __launch_bounds__(256, 3) void conv_kernel(
        const signed char* __restrict__ xq, const signed char* __restrict__ wq,
        const float* __restrict__ bias, const unsigned* __restrict__ scales,
        float* __restrict__ out) {
    __shared__ signed char smem[54272];

    const int tid = threadIdx.x;
    const int lane = tid & 63;
    const int wv = tid >> 6;        // 0..3
    const int ln = lane & 15;
    const int g  = lane >> 4;

    // XCD swizzle: 1792 = 8 x 224; wg pairs (cot 0/1) share the same px window
    const int bid = blockIdx.x;
    const int wg  = (bid & 7) * 224 + (bid >> 3);
    const int pxt = wg >> 1;            // 0..895
    const int cot = wg & 1;
    const int px_blk = pxt * 112;
    const int cotoff = cot * 8192;

    const int b0 = pxt / 28;            // image
    const int h0 = (pxt % 28) * 2;      // first output row of the pair

    // A staging: wave stages 2x1KB contiguous (wq slice layout == A-LDS layout)
    const int aoff0 = wv * 1024 + lane * 16;
    const int aoff1 = aoff0 + 4096;

    // per-lane window pixel index for each j: px_local = j*16+ln -> ph*58+pw
    int px58v[7];
#pragma unroll
    for (int j = 0; j < 7; ++j) {
        const int pl = j * 16 + ln;
        px58v[j] = pl + (pl >= 56 ? 2 : 0);
    }

    // ---- prologue: stage B window (29696B) coalesced, transpose into LDS ----
    const signed char* win = xq + (long)(b0 * HP + h0) * WP * CIN;
    int4v wbuf[8];
#pragma unroll
    for (int k = 0; k < 8; ++k) {
        const int u = tid + k * 256;
        if (u < 1856) wbuf[k] = *(const int4v*)(win + u * 16);
    }
#pragma unroll
    for (int k = 0; k < 8; ++k) {
        const int u = tid + k * 256;          // px58 = u>>3, ci16 = u&7
        if (u < 1856)
            *(int4v*)&smem[BWIN + (u & 7) * GSTR + (u >> 3) * 16] = wbuf[k];
    }

#define STAGE_A(c) { const int bf_ = (c) % 3; \
    gld_lds16(wq + (c) * WCHUNK + cotoff + aoff0, &smem[bf_ * 8192 + aoff0]); \
    gld_lds16(wq + (c) * WCHUNK + cotoff + aoff1, &smem[bf_ * 8192 + aoff1]); }

    STAGE_A(0);
    STAGE_A(1);
    asm volatile("s_waitcnt lgkmcnt(0)" ::: "memory");   // B-window ds_writes done pre-barrier

#define TAP58(c) ((((c) >> 1) / 3) * 58 + (((c) >> 1) % 3))
#define LDA_(i) (*(const int4v*)&smem[buf * 8192 + g * 2048 + (wv * 32 + (i) * 16 + ln) * 16])
#define LDB_(c, j) (*(const int4v*)&smem[BWIN + (((c) & 1) * 4 + g) * GSTR + (px58v[j] + TAP58(c)) * 16])
#define MM(i, j, A, Bv) acc[i][j] = __builtin_amdgcn_mfma_i32_16x16x64_i8(A, Bv, acc[i][j], 0, 0, 0)

#define CHUNK(c, VM) { \
    const int buf = (c) % 3; \
    asm volatile("s_waitcnt vmcnt(" #VM ")\n\ts_barrier" ::: "memory"); \
    if ((c) + 2 < NCHUNK) STAGE_A((c) + 2); \
    int4v Bf0 = LDB_(c, 0), Bf1 = LDB_(c, 1), Bf2 = LDB_(c, 2), Bf3 = LDB_(c, 3); \
    int4v Bf4 = LDB_(c, 4), Bf5 = LDB_(c, 5), Bf6 = LDB_(c, 6); \
    int4v Af0 = LDA_(0), Af1 = LDA_(1); \
    __builtin_amdgcn_s_setprio(1); \
    MM(0, 0, Af0, Bf0); MM(1, 0, Af1, Bf0); MM(0, 1, Af0, Bf1); MM(1, 1, Af1, Bf1); \
    MM(0, 2, Af0, Bf2); MM(1, 2, Af1, Bf2); MM(0, 3, Af0, Bf3); MM(1, 3, Af1, Bf3); \
    MM(0, 4, Af0, Bf4); MM(1, 4, Af1, Bf4); MM(0, 5, Af0, Bf5); MM(1, 5, Af1, Bf5); \
    MM(0, 6, Af0, Bf6); MM(1, 6, Af1, Bf6); \
    __builtin_amdgcn_s_setprio(0); }

    int4v acc[2][7] = {};
    CHUNK(0,  2) CHUNK(1,  2) CHUNK(2,  2) CHUNK(3,  2) CHUNK(4,  2) CHUNK(5,  2)
    CHUNK(6,  2) CHUNK(7,  2) CHUNK(8,  2) CHUNK(9,  2) CHUNK(10, 2) CHUNK(11, 2)
    CHUNK(12, 2) CHUNK(13, 2) CHUNK(14, 2) CHUNK(15, 2) CHUNK(16, 2) CHUNK(17, 0)
#undef CHUNK
#undef MM
#undef LDB_
#undef LDA_
#undef TAP58
#undef STAGE_A

    const float ax = __uint_as_float(scales[0]);
    const float aw = __uint_as_float(scales[1]);
    const float inv = 1.0f / ((127.0f / ax) * (127.0f / aw));

    // -------- epilogue: LDS transpose in 32-co rounds -> float4 stores --------
    // acc (i,j,r): co = cot*128 + wv*32 + i*16 + g*4 + r; px_local = j*16 + ln
    __syncthreads();
    float* ldsT = (float*)smem;            // [32 rows][stride 116 f32] = 14848 B

#pragma unroll
    for (int rnd = 0; rnd < 4; ++rnd) {
        if (wv == rnd) {                   // the wave holding this 32-co band stages it
#pragma unroll
            for (int i = 0; i < 2; ++i)
#pragma unroll
                for (int r = 0; r < 4; ++r) {
                    const int cl = i * 16 + g * 4 + r;   // 0..31
#pragma unroll
                    for (int j = 0; j < 7; ++j)
                        ldsT[cl * 116 + j * 16 + ln] = (float)acc[i][j][r] * inv;
                }
        }
        __syncthreads();
#pragma unroll
        for (int it = 0; it < 4; ++it) {
            const int idx = it * 256 + tid;            // 896 float4s = 32 rows x 28
            if (idx < 896) {
                const int row = idx / 28, c4 = idx - row * 28;
                const int co = cot * 128 + rnd * 32 + row;
                float4 v = *(float4*)&ldsT[row * 116 + c4 * 4];
                const float bsv = bias[co];
                v.x += bsv; v.y += bsv; v.z += bsv; v.w += bsv;
                *(float4*)&out[((long)b0 * COUT + co) * HWP + h0 * 56 + c4 * 4] = v;
            }
        }
        if (rnd < 3) __syncthreads();
    }
}

extern "C" void kernel_launch(void* const* d_in, const int* in_sizes, int n_in,
                              void* d_out, int out_size, void* d_ws, size_t ws_size,
                              hipStream_t stream) {
    const float* x  = (const float*)d_in[0];
    const float* wt = (const float*)d_in[1];
    const float* bs = (const float*)d_in[2];
    float* out = (float*)d_out;

    unsigned* scales = (unsigned*)d_ws;                  // [0]=amax_x, [1]=amax_w (bits)
    const size_t XQ_OFF   = 256;
    const size_t XQ_BYTES = (size_t)B_ * HP * WP * CIN;  // 13,778,944
    signed char* xq = (signed char*)d_ws + XQ_OFF;
    signed char* wq = xq + XQ_BYTES;

    hipMemsetAsync(d_ws, 0, 8, stream);                  // zero the two amax slots

    const long n4x = (long)B_ * CIN * H_ * W_ / 4;
    const long n4w = (long)COUT * CIN * 9 / 4;
    amax_kernel<<<2176, 256, 0, stream>>>((const float4*)x, n4x, (const float4*)wt, n4w, scales);

    quant_x_kernel<<<B_ * H_, 256, 0, stream>>>(x, scales, xq);
    quant_w_kernel<<<(COUT * 9 * 32 + 255) / 256, 256, 0, stream>>>(wt, scales, wq);

    conv_kernel<<<2 * NPIX / 112, 256, 0, stream>>>(xq, wq, bs, scales, out);
}

// Round 9
// 211.761 us; speedup vs baseline: 1.1371x; 1.0460x over previous
//
#include <hip/hip_runtime.h>

// int8 quantized conv2d 3x3 s1 p1. B=32 Cin=128 H=W=56 Cout=256.
// Implicit GEMM, raw-window B reuse + 64co wave tiles (MFMA-per-LDS-read 2x).
// Block: 256 thr = 4 waves, tile 256co x 112px (2 output rows); wave 64co x 112px.
// LDS: A ring 3x16KB @ [0,49152); B window [4 rows][58][128] transposed to
// [ci16 g][232 px][16] with GSTR=3728 (16B pad -> conflict-free writes).
// K-loop: {vmcnt(4); s_barrier} -> STAGE_A(c+2) (4 gld_lds) -> 4A+7B ds_read
// -> 28 MFMA. 896 blocks = 8 XCDs x 112, swizzled.

#define B_    32
#define CIN   128
#define H_    56
#define W_    56
#define COUT  256
#define HP    58
#define WP    58
#define HWP   (H_*W_)        // 3136
#define NPIX  (B_*HWP)       // 100352
#define NCHUNK 18            // K=1152 / 64
#define WCHUNK 16384         // wq bytes per chunk = 256co * 64B
#define BWIN  49152          // LDS offset of B window
#define GSTR  3728           // B window stride per ci16 group = 232*16 + 16 pad

typedef int int4v __attribute__((ext_vector_type(4)));

__device__ __forceinline__ void gld_lds16(const void* g, void* l) {
    __builtin_amdgcn_global_load_lds(
        (const __attribute__((address_space(1))) unsigned int*)g,
        (__attribute__((address_space(3))) unsigned int*)l, 16, 0, 0);
}

// ---------------- fused amax over x and w ----------------
__global__ __launch_bounds__(256) void amax_kernel(const float4* __restrict__ x, long n4x,
                                                   const float4* __restrict__ wt, long n4w,
                                                   unsigned* __restrict__ scales) {
    const float4* p; long n4; unsigned* slot; long start, stride;
    if (blockIdx.x < 2048) {
        p = x; n4 = n4x; slot = scales;
        start = (long)blockIdx.x * 256 + threadIdx.x; stride = 2048L * 256;
    } else {
        p = wt; n4 = n4w; slot = scales + 1;
        start = (long)(blockIdx.x - 2048) * 256 + threadIdx.x; stride = 128L * 256;
    }
    float m = 0.f;
    for (long i = start; i < n4; i += stride) {
        float4 v = p[i];
        m = fmaxf(m, fmaxf(fmaxf(fabsf(v.x), fabsf(v.y)), fmaxf(fabsf(v.z), fabsf(v.w))));
    }
    __shared__ float red[256];
    red[threadIdx.x] = m; __syncthreads();
    for (int s = 128; s > 0; s >>= 1) {
        if (threadIdx.x < s) red[threadIdx.x] = fmaxf(red[threadIdx.x], red[threadIdx.x + s]);
        __syncthreads();
    }
    if (threadIdx.x == 0) atomicMax(slot, __float_as_uint(red[0]));  // all >=0
}

// ---------------- quantize x: NCHW f32 -> padded NHWC int8 (+ border zeroing) ----------------
__global__ __launch_bounds__(256) void quant_x_kernel(const float* __restrict__ x,
        const unsigned* __restrict__ scales, signed char* __restrict__ xq) {
    const int bh = blockIdx.x;
    const int b = bh / H_, h = bh % H_;
    const float sx = 127.0f / __uint_as_float(scales[0]);
    __shared__ int ldsq[W_ * 33];
    const int tid = threadIdx.x;

    // ---- border padding; disjoint rows per block ----
    int4 z; z.x = 0; z.y = 0; z.z = 0; z.w = 0;
    int4* prow = (int4*)(xq + ((long)b * HP + h + 1) * WP * CIN);
    if (tid < 8) prow[tid] = z;                       // col 0 of padded row h+1
    else if (tid < 16) prow[456 + tid - 8] = z;       // col 57 (57*8=456)
    if (h == 0) {
        int4* r0 = (int4*)(xq + (long)b * HP * WP * CIN);
        for (int i = tid; i < 464; i += 256) r0[i] = z;       // padded row 0
    } else if (h == H_ - 1) {
        int4* rt = (int4*)(xq + ((long)b * HP + 57) * WP * CIN);
        for (int i = tid; i < 464; i += 256) rt[i] = z;       // padded row 57
    }

    const int w = tid & 63;
    const int chi = tid >> 6;   // 0..3
    if (w < W_) {
        const float* xb = x + (long)b * CIN * HWP + h * W_ + w;
#pragma unroll
        for (int it = 0; it < 8; ++it) {
            const int c4 = it * 4 + chi;     // 0..31
            int pk = 0;
#pragma unroll
            for (int u = 0; u < 4; ++u) {
                float v = xb[(long)(c4 * 4 + u) * HWP];
                float q = fminf(127.f, fmaxf(-127.f, rintf(v * sx)));
                pk |= ((int)q & 0xff) << (u * 8);
            }
            ldsq[w * 33 + c4] = pk;
        }
    }
    __syncthreads();
    int4* dst = (int4*)(xq + (((long)b * HP + h + 1) * WP + 1) * CIN);
    for (int idx = tid; idx < W_ * 8; idx += 256) {
        const int ww = idx >> 3, c16 = idx & 7;
        int4 v;
        v.x = ldsq[ww * 33 + c16 * 4 + 0];
        v.y = ldsq[ww * 33 + c16 * 4 + 1];
        v.z = ldsq[ww * 33 + c16 * 4 + 2];
        v.w = ldsq[ww * 33 + c16 * 4 + 3];
        dst[ww * 8 + c16] = v;
    }
}

// ---------------- quantize w: OIHW f32 -> packed [chunk][cohalf][g][co128][16] int8 ----------------
__global__ __launch_bounds__(256) void quant_w_kernel(const float* __restrict__ wt,
        const unsigned* __restrict__ scales, signed char* __restrict__ wq) {
    const int id = blockIdx.x * 256 + threadIdx.x;   // 73728 total
    if (id >= COUT * 9 * 32) return;
    const float sw = 127.0f / __uint_as_float(scales[1]);
    const int co = id / 288;
    const int r  = id % 288;
    const int t  = r / 32;    // tap
    const int c4 = r % 32;    // ci/4
    int pk = 0;
#pragma unroll
    for (int u = 0; u < 4; ++u) {
        float v = wt[(co * CIN + c4 * 4 + u) * 9 + t];
        float q = fminf(127.f, fmaxf(-127.f, rintf(v * sw)));
        pk |= ((int)q & 0xff) << (u * 8);
    }
    const int k = t * CIN + c4 * 4;
    const int chunk = k >> 6;
    const int o = k & 63;
    *(int*)(wq + (long)chunk * WCHUNK + (co >> 7) * 8192 +
            (o >> 4) * 2048 + (co & 127) * 16 + (o & 15)) = pk;
}

// ---------------- conv: raw-window B + A-LDS ring, 64co waves, counted-vmcnt ----------------
__global__ __launch_bounds__(256, 2) void conv_kernel(
        const signed char* __restrict__ xq, const signed char* __restrict__ wq,
        const float* __restrict__ bias, const unsigned* __restrict__ scales,
        float* __restrict__ out) {
    __shared__ signed char smem[78976];   // A ring 49152 + B window 29824

    const int tid = threadIdx.x;
    const int lane = tid & 63;
    const int wv = tid >> 6;        // 0..3 = co band
    const int ln = lane & 15;
    const int g  = lane >> 4;

    // XCD swizzle: 896 = 8 x 112
    const int bid = blockIdx.x;
    const int wg  = (bid & 7) * 112 + (bid >> 3);     // = pxt
    const int b0 = wg / 28;             // image
    const int h0 = (wg % 28) * 2;       // first output row of the pair

    // A staging: 4 gld_lds/chunk, linear copy of the 16KB chunk
    const int koff = wv * 1024 + lane * 16;

    // per-lane window pixel index for each j: px_local = j*16+ln -> ph*58+pw
    int px58v[7];
#pragma unroll
    for (int j = 0; j < 7; ++j) {
        const int pl = j * 16 + ln;
        px58v[j] = pl + (pl >= 56 ? 2 : 0);
    }

    // ---- prologue: stage B window (29696B) coalesced, transpose into LDS ----
    const signed char* win = xq + (long)(b0 * HP + h0) * WP * CIN;
    int4v wbuf[8];
#pragma unroll
    for (int k = 0; k < 8; ++k) {
        const int u = tid + k * 256;
        if (u < 1856) wbuf[k] = *(const int4v*)(win + u * 16);
    }
#pragma unroll
    for (int k = 0; k < 8; ++k) {
        const int u = tid + k * 256;          // px58 = u>>3, ci16 = u&7
        if (u < 1856)
            *(int4v*)&smem[BWIN + (u & 7) * GSTR + (u >> 3) * 16] = wbuf[k];
    }

#define STAGE_A(c) { const int bf_ = (c) % 3; \
    gld_lds16(wq + (c) * WCHUNK + koff,         &smem[bf_ * 16384 + koff]); \
    gld_lds16(wq + (c) * WCHUNK + koff + 4096,  &smem[bf_ * 16384 + koff + 4096]); \
    gld_lds16(wq + (c) * WCHUNK + koff + 8192,  &smem[bf_ * 16384 + koff + 8192]); \
    gld_lds16(wq + (c) * WCHUNK + koff + 12288, &smem[bf_ * 16384 + koff + 12288]); }

    STAGE_A(0);
    __builtin_amdgcn_sched_barrier(0);   // pin body order for FIFO vmcnt counting
    STAGE_A(1);
    asm volatile("s_waitcnt lgkmcnt(0)" ::: "memory");   // B-window ds_writes visible

#define TAP58(c) ((((c) >> 1) / 3) * 58 + (((c) >> 1) % 3))
#define LDA_(i) (*(const int4v*)&smem[buf * 16384 + (wv >> 1) * 8192 + g * 2048 + \
                                      ((wv & 1) * 64 + (i) * 16 + ln) * 16])
#define LDB_(c, j) (*(const int4v*)&smem[BWIN + (((c) & 1) * 4 + g) * GSTR + (px58v[j] + TAP58(c)) * 16])
#define MM(i, j, A, Bv) acc[i][j] = __builtin_amdgcn_mfma_i32_16x16x64_i8(A, Bv, acc[i][j], 0, 0, 0)

#define CHUNK(c, VM) { \
    const int buf = (c) % 3; \
    asm volatile("s_waitcnt vmcnt(" #VM ")\n\ts_barrier" ::: "memory"); \
    if ((c) + 2 < NCHUNK) STAGE_A((c) + 2); \
    int4v Bf0 = LDB_(c, 0), Bf1 = LDB_(c, 1), Bf2 = LDB_(c, 2), Bf3 = LDB_(c, 3); \
    int4v Bf4 = LDB_(c, 4), Bf5 = LDB_(c, 5), Bf6 = LDB_(c, 6); \
    int4v Af0 = LDA_(0), Af1 = LDA_(1), Af2 = LDA_(2), Af3 = LDA_(3); \
    __builtin_amdgcn_s_setprio(1); \
    MM(0, 0, Af0, Bf0); MM(1, 0, Af1, Bf0); MM(2, 0, Af2, Bf0); MM(3, 0, Af3, Bf0); \
    MM(0, 1, Af0, Bf1); MM(1, 1, Af1, Bf1); MM(2, 1, Af2, Bf1); MM(3, 1, Af3, Bf1); \
    MM(0, 2, Af0, Bf2); MM(1, 2, Af1, Bf2); MM(2, 2, Af2, Bf2); MM(3, 2, Af3, Bf2); \
    MM(0, 3, Af0, Bf3); MM(1, 3, Af1, Bf3); MM(2, 3, Af2, Bf3); MM(3, 3, Af3, Bf3); \
    MM(0, 4, Af0, Bf4); MM(1, 4, Af1, Bf4); MM(2, 4, Af2, Bf4); MM(3, 4, Af3, Bf4); \
    MM(0, 5, Af0, Bf5); MM(1, 5, Af1, Bf5); MM(2, 5, Af2, Bf5); MM(3, 5, Af3, Bf5); \
    MM(0, 6, Af0, Bf6); MM(1, 6, Af1, Bf6); MM(2, 6, Af2, Bf6); MM(3, 6, Af3, Bf6); \
    __builtin_amdgcn_s_setprio(0); }

    int4v acc[4][7] = {};
    CHUNK(0,  4) CHUNK(1,  4) CHUNK(2,  4) CHUNK(3,  4) CHUNK(4,  4) CHUNK(5,  4)
    CHUNK(6,  4) CHUNK(7,  4) CHUNK(8,  4) CHUNK(9,  4) CHUNK(10, 4) CHUNK(11, 4)
    CHUNK(12, 4) CHUNK(13, 4) CHUNK(14, 4) CHUNK(15, 4) CHUNK(16, 4) CHUNK(17, 0)
#undef CHUNK
#undef MM
#undef LDB_
#undef LDA_
#undef TAP58
#undef STAGE_A

    const float ax = __uint_as_float(scales[0]);
    const float aw = __uint_as_float(scales[1]);
    const float inv = 1.0f / ((127.0f / ax) * (127.0f / aw));

    // -------- epilogue: LDS transpose in 64-co rounds -> float4 stores --------
    // acc (i,j,r): co = wv*64 + i*16 + g*4 + r; px_local = j*16 + ln
    __syncthreads();
    float* ldsT = (float*)smem;            // [64 rows][stride 116 f32] = 29696 B

#pragma unroll
    for (int rnd = 0; rnd < 4; ++rnd) {
        if (wv == rnd) {                   // the wave holding this 64-co band stages it
#pragma unroll
            for (int i = 0; i < 4; ++i)
#pragma unroll
                for (int r = 0; r < 4; ++r) {
                    const int cl = i * 16 + g * 4 + r;   // 0..63
#pragma unroll
                    for (int j = 0; j < 7; ++j)
                        ldsT[cl * 116 + j * 16 + ln] = (float)acc[i][j][r] * inv;
                }
        }
        __syncthreads();
#pragma unroll
        for (int it = 0; it < 7; ++it) {
            const int idx = it * 256 + tid;            // 1792 float4s = 64 rows x 28
            const int row = idx / 28, c4 = idx - row * 28;
            const int co = rnd * 64 + row;
            float4 v = *(float4*)&ldsT[row * 116 + c4 * 4];
            const float bsv = bias[co];
            v.x += bsv; v.y += bsv; v.z += bsv; v.w += bsv;
            *(float4*)&out[((long)b0 * COUT + co) * HWP + h0 * 56 + c4 * 4] = v;
        }
        if (rnd < 3) __syncthreads();
    }
}

extern "C" void kernel_launch(void* const* d_in, const int* in_sizes, int n_in,
                              void* d_out, int out_size, void* d_ws, size_t ws_size,
                              hipStream_t stream) {
    const float* x  = (const float*)d_in[0];
    const float* wt = (const float*)d_in[1];
    const float* bs = (const float*)d_in[2];
    float* out = (float*)d_out;

    unsigned* scales = (unsigned*)d_ws;                  // [0]=amax_x, [1]=amax_w (bits)
    const size_t XQ_OFF   = 256;
    const size_t XQ_BYTES = (size_t)B_ * HP * WP * CIN;  // 13,778,944
    signed char* xq = (signed char*)d_ws + XQ_OFF;
    signed char* wq = xq + XQ_BYTES;

    hipMemsetAsync(d_ws, 0, 8, stream);                  // zero the two amax slots

    const long n4x = (long)B_ * CIN * H_ * W_ / 4;
    const long n4w = (long)COUT * CIN * 9 / 4;
    amax_kernel<<<2176, 256, 0, stream>>>((const float4*)x, n4x, (const float4*)wt, n4w, scales);

    quant_x_kernel<<<B_ * H_, 256, 0, stream>>>(x, scales, xq);
    quant_w_kernel<<<(COUT * 9 * 32 + 255) / 256, 256, 0, stream>>>(wt, scales, wq);

    conv_kernel<<<NPIX / 112, 256, 0, stream>>>(xq, wq, bs, scales, out);
}